// Round 1
// baseline (5346.693 us; speedup 1.0000x reference)
//
#include <hip/hip_runtime.h>
#include <hip/hip_bf16.h>
#include <cmath>

static constexpr int NB   = 2;
static constexpr int NH   = 8;
static constexpr int NSEQ = 2048;
static constexpr int DM   = 1024;   // model dim
static constexpr int DH   = 64;     // head dim
static constexpr int DI   = 512;    // NH*DH
static constexpr int MROWS = NB * NSEQ;  // 4096

__device__ __forceinline__ float sigm(float x) { return 1.0f / (1.0f + expf(-x)); }
__device__ __forceinline__ float silu(float x) { return x / (1.0f + expf(-x)); }

// C[am0..+64, bn0..+64] += A[m,k] * Bt[n,k]  (i.e. C = A * Bt^T), K range [k0,k1)
// As/Bs: [16][68] f32 LDS tiles. 256 threads, 4x4 microtile each.
__device__ __forceinline__ void gemm_abT(const float* __restrict__ A, int lda,
                                         const float* __restrict__ Bt, int ldb,
                                         int am0, int bn0, int k0, int k1,
                                         float (&acc)[4][4], float* As, float* Bs)
{
    const int tid = threadIdx.x;
    const int tm = tid >> 4, tn = tid & 15;
    const int lk = tid & 15, lr = tid >> 4;
    for (int kt = k0; kt < k1; kt += 16) {
#pragma unroll
        for (int p = 0; p < 4; ++p) {
            const int r = lr + p * 16;
            As[lk * 68 + r] = A[(size_t)(am0 + r) * lda + (kt + lk)];
            Bs[lk * 68 + r] = Bt[(size_t)(bn0 + r) * ldb + (kt + lk)];
        }
        __syncthreads();
#pragma unroll
        for (int kk = 0; kk < 16; ++kk) {
            const float4 av = *(const float4*)(As + kk * 68 + tm * 4);
            const float4 bv = *(const float4*)(Bs + kk * 68 + tn * 4);
            const float a[4] = {av.x, av.y, av.z, av.w};
            const float b[4] = {bv.x, bv.y, bv.z, bv.w};
#pragma unroll
            for (int i = 0; i < 4; ++i)
#pragma unroll
                for (int j = 0; j < 4; ++j)
                    acc[i][j] = fmaf(a[i], b[j], acc[i][j]);
        }
        __syncthreads();
    }
}

// ---------------- QKV projection: qkv[t][b][h][n][d] = (x @ Wqkv^T) scattered ----
__global__ __launch_bounds__(256)
void k_proj(const float* __restrict__ x, const float* __restrict__ Wqkv,
            float* __restrict__ qkv)
{
    __shared__ __align__(16) float As[16 * 68];
    __shared__ __align__(16) float Bs[16 * 68];
    float acc[4][4] = {};
    const int bx = blockIdx.x, by = blockIdx.y;
    gemm_abT(x, DM, Wqkv, DM, by * 64, bx * 64, 0, DM, acc, As, Bs);
    const int tm = threadIdx.x >> 4, tn = threadIdx.x & 15;
#pragma unroll
    for (int i = 0; i < 4; ++i) {
        const int m = by * 64 + tm * 4 + i;
        const int b_ = m >> 11, npos = m & 2047;
#pragma unroll
        for (int j = 0; j < 4; ++j) {
            const int n = bx * 64 + tn * 4 + j;
            const int t = n >> 9;            // /512
            const int head = (n >> 6) & 7;
            const int dd = n & 63;
            float v = acc[i][j];
            if (t == 0 || t == 3) v *= 0.125f;   // SCALE on qu, qc
            qkv[((((size_t)t * NB + b_) * NH + head) * NSEQ + npos) * DH + dd] = v;
        }
    }
}

// ---------------- term1 = mask_lower(qc_s @ vu^T) --------------------------------
__global__ __launch_bounds__(256)
void k_term1(const float* __restrict__ qc, const float* __restrict__ vu,
             float* __restrict__ t1)
{
    const int bx = blockIdx.x, by = blockIdx.y;  // bx = j tile, by = i tile
    if (bx > by) return;                         // upper tiles never read
    __shared__ __align__(16) float As[16 * 68];
    __shared__ __align__(16) float Bs[16 * 68];
    float acc[4][4] = {};
    gemm_abT(qc, DH, vu, DH, by * 64, bx * 64, 0, DH, acc, As, Bs);
    const int tm = threadIdx.x >> 4, tn = threadIdx.x & 15;
#pragma unroll
    for (int i = 0; i < 4; ++i) {
        const int gi = by * 64 + tm * 4 + i;
#pragma unroll
        for (int j = 0; j < 4; ++j) {
            const int gj = bx * 64 + tn * 4 + j;
            t1[(size_t)gi * NSEQ + gj] = (gj <= gi) ? acc[i][j] : 0.0f;
        }
    }
}

// ---------------- lookahead = mask_strict_upper(sigmoid(qu_s @ ku^T)) ------------
__global__ __launch_bounds__(256)
void k_look(const float* __restrict__ qu, const float* __restrict__ ku,
            float* __restrict__ lk_)
{
    const int bx = blockIdx.x, by = blockIdx.y;  // bx = j tile, by = k tile
    if (bx < by) return;                         // lower tiles never read
    __shared__ __align__(16) float As[16 * 68];
    __shared__ __align__(16) float Bs[16 * 68];
    float acc[4][4] = {};
    gemm_abT(qu, DH, ku, DH, by * 64, bx * 64, 0, DH, acc, As, Bs);
    const int tm = threadIdx.x >> 4, tn = threadIdx.x & 15;
#pragma unroll
    for (int i = 0; i < 4; ++i) {
        const int gk = by * 64 + tm * 4 + i;
#pragma unroll
        for (int j = 0; j < 4; ++j) {
            const int gj = bx * 64 + tn * 4 + j;
            lk_[(size_t)gk * NSEQ + gj] = (gj > gk) ? sigm(acc[i][j]) : 0.0f;
        }
    }
}

// ---------------- scores = (qc_s @ kc^T) - silu(term1 @ look^T), k<=i only -------
__global__ __launch_bounds__(256)
void k_scores(const float* __restrict__ t1, const float* __restrict__ lk_,
              const float* __restrict__ qc, const float* __restrict__ kc,
              float* __restrict__ sc)
{
    const int bx = blockIdx.x, by = blockIdx.y;  // bx = k tile, by = i tile
    if (bx > by) return;                         // strictly-upper: softmax never reads
    __shared__ __align__(16) float As[16 * 68];
    __shared__ __align__(16) float Bs[16 * 68];
    float su[4][4] = {};
    // product nonzero only for k < j <= i  ->  j-blocks [bx, by]
    gemm_abT(t1, NSEQ, lk_, NSEQ, by * 64, bx * 64, bx * 64, (by + 1) * 64, su, As, Bs);
    float scf[4][4] = {};
    gemm_abT(qc, DH, kc, DH, by * 64, bx * 64, 0, DH, scf, As, Bs);
    const int tm = threadIdx.x >> 4, tn = threadIdx.x & 15;
#pragma unroll
    for (int i = 0; i < 4; ++i) {
        const int gi = by * 64 + tm * 4 + i;
#pragma unroll
        for (int j = 0; j < 4; ++j) {
            const int gk = bx * 64 + tn * 4 + j;
            if (gk <= gi)
                sc[(size_t)gi * NSEQ + gk] = scf[i][j] - silu(su[i][j]);
        }
    }
}

// ---------------- row softmax over k<=i; zero k>i (in place) ---------------------
__global__ __launch_bounds__(256)
void k_softmax(float* __restrict__ sc)
{
    const int i = blockIdx.x;
    const int tid = threadIdx.x;
    float* row = sc + (size_t)i * NSEQ;
    const int nv = i + 1;
    __shared__ float red[256];
    float m = -INFINITY;
    for (int k = tid; k < nv; k += 256) m = fmaxf(m, row[k]);
    red[tid] = m; __syncthreads();
    for (int s = 128; s > 0; s >>= 1) {
        if (tid < s) red[tid] = fmaxf(red[tid], red[tid + s]);
        __syncthreads();
    }
    m = red[0]; __syncthreads();
    float sum = 0.0f;
    for (int k = tid; k < nv; k += 256) sum += expf(row[k] - m);
    red[tid] = sum; __syncthreads();
    for (int s = 128; s > 0; s >>= 1) {
        if (tid < s) red[tid] += red[tid + s];
        __syncthreads();
    }
    const float inv = 1.0f / red[0];
    for (int k = tid; k < nv; k += 256) row[k] = expf(row[k] - m) * inv;
    for (int k = nv + tid; k < NSEQ; k += 256) row[k] = 0.0f;
}

// ---------------- out_h = attn @ vc  (k-blocks 0..ti only) -----------------------
__global__ __launch_bounds__(256)
void k_pv(const float* __restrict__ attn, const float* __restrict__ vc,
          float* __restrict__ attno, int b, int h)
{
    const int by = blockIdx.x;   // i tile
    __shared__ __align__(16) float As[16 * 68];
    __shared__ __align__(16) float Bs[16 * 68];
    float acc[4][4] = {};
    const int tid = threadIdx.x;
    const int tm = tid >> 4, tn = tid & 15;
    const int lk = tid & 15, lr = tid >> 4;
    const int k1 = (by + 1) * 64;
    for (int kt = 0; kt < k1; kt += 16) {
#pragma unroll
        for (int p = 0; p < 4; ++p) {
            const int r = lr + p * 16;
            As[lk * 68 + r] = attn[(size_t)(by * 64 + r) * NSEQ + kt + lk];
        }
#pragma unroll
        for (int p = 0; p < 4; ++p) {
            const int kk = (tid >> 6) + p * 4;
            const int n = tid & 63;
            Bs[kk * 68 + n] = vc[(size_t)(kt + kk) * DH + n];
        }
        __syncthreads();
#pragma unroll
        for (int kk = 0; kk < 16; ++kk) {
            const float4 av = *(const float4*)(As + kk * 68 + tm * 4);
            const float4 bv = *(const float4*)(Bs + kk * 68 + tn * 4);
            const float a[4] = {av.x, av.y, av.z, av.w};
            const float bb[4] = {bv.x, bv.y, bv.z, bv.w};
#pragma unroll
            for (int i = 0; i < 4; ++i)
#pragma unroll
                for (int j = 0; j < 4; ++j)
                    acc[i][j] = fmaf(a[i], bb[j], acc[i][j]);
        }
        __syncthreads();
    }
#pragma unroll
    for (int i = 0; i < 4; ++i) {
        const int gi = by * 64 + tm * 4 + i;
#pragma unroll
        for (int j = 0; j < 4; ++j) {
            const int gdd = tn * 4 + j;
            attno[((size_t)b * NSEQ + gi) * DI + h * DH + gdd] = acc[i][j];
        }
    }
}

// ---------------- final = attno @ W_out^T ----------------------------------------
__global__ __launch_bounds__(256)
void k_outproj(const float* __restrict__ attno, const float* __restrict__ Wout,
               float* __restrict__ out)
{
    __shared__ __align__(16) float As[16 * 68];
    __shared__ __align__(16) float Bs[16 * 68];
    float acc[4][4] = {};
    const int bx = blockIdx.x, by = blockIdx.y;
    gemm_abT(attno, DI, Wout, DI, by * 64, bx * 64, 0, DI, acc, As, Bs);
    const int tm = threadIdx.x >> 4, tn = threadIdx.x & 15;
#pragma unroll
    for (int i = 0; i < 4; ++i) {
        const int m = by * 64 + tm * 4 + i;
#pragma unroll
        for (int j = 0; j < 4; ++j) {
            const int o = bx * 64 + tn * 4 + j;
            out[(size_t)m * DM + o] = acc[i][j];
        }
    }
}

extern "C" void kernel_launch(void* const* d_in, const int* in_sizes, int n_in,
                              void* d_out, int out_size, void* d_ws, size_t ws_size,
                              hipStream_t stream)
{
    const float* x    = (const float*)d_in[0];
    const float* Wqkv = (const float*)d_in[1];
    const float* Wout = (const float*)d_in[2];
    float* out = (float*)d_out;

    // ws layout (floats): qkv[6][B][H][N][64] | t1[N][N] | look[N][N] | sc[N][N] | attno[B][N][512]
    const size_t qkv_elems = (size_t)6 * NB * NH * NSEQ * DH;   // 12,582,912
    const size_t nn = (size_t)NSEQ * NSEQ;                      // 4,194,304
    const size_t attno_elems = (size_t)NB * NSEQ * DI;          // 2,097,152
    const size_t need = (qkv_elems + 3 * nn + attno_elems) * sizeof(float);
    if (ws_size < need) return;  // insufficient scratch; fail cleanly

    float* qkv   = (float*)d_ws;
    float* t1    = qkv + qkv_elems;
    float* lk_   = t1 + nn;
    float* sc    = lk_ + nn;
    float* attno = sc + nn;

    const dim3 blk(256);
    k_proj<<<dim3(3072 / 64, MROWS / 64), blk, 0, stream>>>(x, Wqkv, qkv);

    for (int b = 0; b < NB; ++b) {
        for (int h = 0; h < NH; ++h) {
            const size_t sl = (size_t)NSEQ * DH;
            const float* qu = qkv + ((size_t)(0 * NB + b) * NH + h) * sl;
            const float* ku = qkv + ((size_t)(1 * NB + b) * NH + h) * sl;
            const float* vu = qkv + ((size_t)(2 * NB + b) * NH + h) * sl;
            const float* qc = qkv + ((size_t)(3 * NB + b) * NH + h) * sl;
            const float* kc = qkv + ((size_t)(4 * NB + b) * NH + h) * sl;
            const float* vc = qkv + ((size_t)(5 * NB + b) * NH + h) * sl;

            k_term1 <<<dim3(32, 32), blk, 0, stream>>>(qc, vu, t1);
            k_look  <<<dim3(32, 32), blk, 0, stream>>>(qu, ku, lk_);
            k_scores<<<dim3(32, 32), blk, 0, stream>>>(t1, lk_, qc, kc, sc);
            k_softmax<<<dim3(NSEQ), blk, 0, stream>>>(sc);
            k_pv    <<<dim3(32), blk, 0, stream>>>(sc, vc, attno, b, h);
        }
    }

    k_outproj<<<dim3(DM / 64, MROWS / 64), blk, 0, stream>>>(attno, Wout, out);
}

// Round 3
// 1571.095 us; speedup vs baseline: 3.4032x; 3.4032x over previous
//
#include <hip/hip_runtime.h>
#include <cmath>

typedef unsigned short ushort_t;
typedef __attribute__((ext_vector_type(8))) short short8;
typedef __attribute__((ext_vector_type(4))) float f32x4;

static constexpr int NB = 2, NH = 8, NSEQ = 2048, DM = 1024, DH = 64, DI = 512;
static constexpr int P = 40;  // LDS pitch (bf16 elems): 80B rows -> 2-way bank aliasing (free)

__device__ __forceinline__ ushort_t f2b(float v) {
    unsigned u = __float_as_uint(v);
    return (ushort_t)((u + 0x7fffu + ((u >> 16) & 1u)) >> 16);  // RTNE
}
__device__ __forceinline__ float b2f(ushort_t b) { return __uint_as_float(((unsigned)b) << 16); }
__device__ __forceinline__ float sigm(float x) { return 1.f / (1.f + expf(-x)); }
__device__ __forceinline__ float silu(float x) { return x / (1.f + expf(-x)); }

#define MFMA16(a, b, c) __builtin_amdgcn_mfma_f32_16x16x32_bf16(a, b, c, 0, 0, 0)

// ---- staging: rows x 32 K-slice into LDS [rows][P] ------------------------------
__device__ __forceinline__ void stage_f32_hl(const float* __restrict__ g, int ldg, int rows,
                                             ushort_t* hi, ushort_t* lo) {
    for (int c = threadIdx.x; c < rows * 4; c += 256) {
        int r = c >> 2, kc = (c & 3) * 8;
        const float* s = g + (size_t)r * ldg + kc;
        float4 f0 = *(const float4*)s, f1 = *(const float4*)(s + 4);
        float f[8] = {f0.x, f0.y, f0.z, f0.w, f1.x, f1.y, f1.z, f1.w};
        short8 hv, lv;
#pragma unroll
        for (int j = 0; j < 8; ++j) {
            ushort_t h = f2b(f[j]);
            hv[j] = (short)h;
            lv[j] = (short)f2b(f[j] - b2f(h));
        }
        *(short8*)(hi + r * P + kc) = hv;
        *(short8*)(lo + r * P + kc) = lv;
    }
}
__device__ __forceinline__ void stage_f32_s(const float* __restrict__ g, int ldg, int rows,
                                            ushort_t* hi) {
    for (int c = threadIdx.x; c < rows * 4; c += 256) {
        int r = c >> 2, kc = (c & 3) * 8;
        const float* s = g + (size_t)r * ldg + kc;
        float4 f0 = *(const float4*)s, f1 = *(const float4*)(s + 4);
        float f[8] = {f0.x, f0.y, f0.z, f0.w, f1.x, f1.y, f1.z, f1.w};
        short8 hv;
#pragma unroll
        for (int j = 0; j < 8; ++j) hv[j] = (short)f2b(f[j]);
        *(short8*)(hi + r * P + kc) = hv;
    }
}
__device__ __forceinline__ void stage_hl(const ushort_t* __restrict__ gh,
                                         const ushort_t* __restrict__ gl, int ldg, int rows,
                                         ushort_t* hi, ushort_t* lo) {
    for (int c = threadIdx.x; c < rows * 4; c += 256) {
        int r = c >> 2, kc = (c & 3) * 8;
        *(short8*)(hi + r * P + kc) = *(const short8*)(gh + (size_t)r * ldg + kc);
        *(short8*)(lo + r * P + kc) = *(const short8*)(gl + (size_t)r * ldg + kc);
    }
}
__device__ __forceinline__ void stage_s(const ushort_t* __restrict__ gh, int ldg, int rows,
                                        ushort_t* hi) {
    for (int c = threadIdx.x; c < rows * 4; c += 256) {
        int r = c >> 2, kc = (c & 3) * 8;
        *(short8*)(hi + r * P + kc) = *(const short8*)(gh + (size_t)r * ldg + kc);
    }
}

// ---- fragment load + MFMA tiles --------------------------------------------------
__device__ __forceinline__ short8 frag(const ushort_t* base, int row0, int lane) {
    return *(const short8*)(base + (row0 + (lane & 15)) * P + (lane >> 4) * 8);
}
__device__ __forceinline__ void mm_hl_4x4(const ushort_t* Ah, const ushort_t* Al,
                                          const ushort_t* Bh, const ushort_t* Bl, int mb, int nb,
                                          int lane, f32x4 (&acc)[4][4]) {
    short8 ah[4], al[4], bh[4], bl[4];
#pragma unroll
    for (int i = 0; i < 4; ++i) { ah[i] = frag(Ah, mb + i * 16, lane); al[i] = frag(Al, mb + i * 16, lane); }
#pragma unroll
    for (int j = 0; j < 4; ++j) { bh[j] = frag(Bh, nb + j * 16, lane); bl[j] = frag(Bl, nb + j * 16, lane); }
#pragma unroll
    for (int i = 0; i < 4; ++i)
#pragma unroll
        for (int j = 0; j < 4; ++j) {
            acc[i][j] = MFMA16(ah[i], bh[j], acc[i][j]);
            acc[i][j] = MFMA16(ah[i], bl[j], acc[i][j]);
            acc[i][j] = MFMA16(al[i], bh[j], acc[i][j]);
        }
}
__device__ __forceinline__ void mm_s_4x4(const ushort_t* Ah, const ushort_t* Bh, int mb, int nb,
                                         int lane, f32x4 (&acc)[4][4]) {
    short8 a[4], b[4];
#pragma unroll
    for (int i = 0; i < 4; ++i) a[i] = frag(Ah, mb + i * 16, lane);
#pragma unroll
    for (int j = 0; j < 4; ++j) b[j] = frag(Bh, nb + j * 16, lane);
#pragma unroll
    for (int i = 0; i < 4; ++i)
#pragma unroll
        for (int j = 0; j < 4; ++j) acc[i][j] = MFMA16(a[i], b[j], acc[i][j]);
}
__device__ __forceinline__ void mm_s_2x4(const ushort_t* Ah, const ushort_t* Bh, int mb, int nb,
                                         int lane, f32x4 (&acc)[2][4]) {
    short8 a[2], b[4];
#pragma unroll
    for (int i = 0; i < 2; ++i) a[i] = frag(Ah, mb + i * 16, lane);
#pragma unroll
    for (int j = 0; j < 4; ++j) b[j] = frag(Bh, nb + j * 16, lane);
#pragma unroll
    for (int i = 0; i < 2; ++i)
#pragma unroll
        for (int j = 0; j < 4; ++j) acc[i][j] = MFMA16(a[i], b[j], acc[i][j]);
}

// ---- proj: qkv = x @ Wqkv^T, scatter to [t][bh][n][64] hi/lo, vc also -> vcT ----
__global__ __launch_bounds__(256) void k_proj(const float* __restrict__ x,
                                              const float* __restrict__ Wq,
                                              ushort_t* __restrict__ qh, ushort_t* __restrict__ ql,
                                              ushort_t* __restrict__ vcT) {
    __shared__ ushort_t Ah[128 * P], Al[128 * P], Bh[128 * P], Bl[128 * P];
    f32x4 acc[4][4] = {};
    const int m0 = blockIdx.y * 128, n0 = blockIdx.x * 128;
    const int l = threadIdx.x & 63, w = threadIdx.x >> 6;
    const int mb = (w >> 1) * 64, nb = (w & 1) * 64;
    for (int k0 = 0; k0 < DM; k0 += 32) {
        stage_f32_hl(x + (size_t)m0 * DM + k0, DM, 128, Ah, Al);
        stage_f32_hl(Wq + (size_t)n0 * DM + k0, DM, 128, Bh, Bl);
        __syncthreads();
        mm_hl_4x4(Ah, Al, Bh, Bl, mb, nb, l, acc);
        __syncthreads();
    }
#pragma unroll
    for (int i = 0; i < 4; ++i)
#pragma unroll
        for (int j = 0; j < 4; ++j)
#pragma unroll
            for (int r = 0; r < 4; ++r) {
                int m = m0 + mb + i * 16 + (l >> 4) * 4 + r;
                int n = n0 + nb + j * 16 + (l & 15);
                float v = acc[i][j][r];
                int t = n >> 9, head = (n >> 6) & 7, dd = n & 63;
                int b = m >> 11, np = m & 2047;
                if (t == 0 || t == 3) v *= 0.125f;
                ushort_t h = f2b(v), lo = f2b(v - b2f(h));
                size_t off = (size_t)(t * 16 + b * 8 + head) * 131072 + (size_t)np * 64 + dd;
                qh[off] = h;
                ql[off] = lo;
                if (t == 5) vcT[(size_t)(b * 8 + head) * 131072 + (size_t)dd * 2048 + np] = h;
            }
}

// ---- t1 = mask_lower(qc_s @ vu^T), hi/lo ----------------------------------------
__global__ __launch_bounds__(256) void k_t1(const ushort_t* __restrict__ qh,
                                            const ushort_t* __restrict__ ql,
                                            ushort_t* __restrict__ t1h, ushort_t* __restrict__ t1l,
                                            int g0) {
    const int bxj = blockIdx.x, byi = blockIdx.y;
    if (bxj > byi) return;
    const int z = blockIdx.z, hh = g0 + z;
    const size_t qco = (size_t)(3 * 16 + hh) * 131072, vuo = (size_t)(2 * 16 + hh) * 131072;
    __shared__ ushort_t Ah[128 * P], Al[128 * P], Bh[128 * P], Bl[128 * P];
    f32x4 acc[4][4] = {};
    const int l = threadIdx.x & 63, w = threadIdx.x >> 6;
    const int mb = (w >> 1) * 64, nb = (w & 1) * 64;
    for (int k0 = 0; k0 < DH; k0 += 32) {
        stage_hl(qh + qco + (size_t)(byi * 128) * 64 + k0, ql + qco + (size_t)(byi * 128) * 64 + k0, 64, 128, Ah, Al);
        stage_hl(qh + vuo + (size_t)(bxj * 128) * 64 + k0, ql + vuo + (size_t)(bxj * 128) * 64 + k0, 64, 128, Bh, Bl);
        __syncthreads();
        mm_hl_4x4(Ah, Al, Bh, Bl, mb, nb, l, acc);
        __syncthreads();
    }
    ushort_t* th = t1h + (size_t)z * 4194304;
    ushort_t* tl = t1l + (size_t)z * 4194304;
#pragma unroll
    for (int i = 0; i < 4; ++i)
#pragma unroll
        for (int j = 0; j < 4; ++j)
#pragma unroll
            for (int r = 0; r < 4; ++r) {
                int gi = byi * 128 + mb + i * 16 + (l >> 4) * 4 + r;
                int gj = bxj * 128 + nb + j * 16 + (l & 15);
                float v = (gj <= gi) ? acc[i][j][r] : 0.f;
                ushort_t h = f2b(v), lo = f2b(v - b2f(h));
                th[(size_t)gi * 2048 + gj] = h;
                tl[(size_t)gi * 2048 + gj] = lo;
            }
}

// ---- look = mask_strict_upper(sigmoid(qu_s @ ku^T)), hi/lo ----------------------
__global__ __launch_bounds__(256) void k_look(const ushort_t* __restrict__ qh,
                                              const ushort_t* __restrict__ ql,
                                              ushort_t* __restrict__ lkh, ushort_t* __restrict__ lkl,
                                              int g0) {
    const int bxj = blockIdx.x, byk = blockIdx.y;
    if (bxj < byk) return;
    const int z = blockIdx.z, hh = g0 + z;
    const size_t quo = (size_t)(0 * 16 + hh) * 131072, kuo = (size_t)(1 * 16 + hh) * 131072;
    __shared__ ushort_t Ah[128 * P], Al[128 * P], Bh[128 * P], Bl[128 * P];
    f32x4 acc[4][4] = {};
    const int l = threadIdx.x & 63, w = threadIdx.x >> 6;
    const int mb = (w >> 1) * 64, nb = (w & 1) * 64;
    for (int k0 = 0; k0 < DH; k0 += 32) {
        stage_hl(qh + quo + (size_t)(byk * 128) * 64 + k0, ql + quo + (size_t)(byk * 128) * 64 + k0, 64, 128, Ah, Al);
        stage_hl(qh + kuo + (size_t)(bxj * 128) * 64 + k0, ql + kuo + (size_t)(bxj * 128) * 64 + k0, 64, 128, Bh, Bl);
        __syncthreads();
        mm_hl_4x4(Ah, Al, Bh, Bl, mb, nb, l, acc);
        __syncthreads();
    }
    ushort_t* lh = lkh + (size_t)z * 4194304;
    ushort_t* ll = lkl + (size_t)z * 4194304;
#pragma unroll
    for (int i = 0; i < 4; ++i)
#pragma unroll
        for (int j = 0; j < 4; ++j)
#pragma unroll
            for (int r = 0; r < 4; ++r) {
                int gk = byk * 128 + mb + i * 16 + (l >> 4) * 4 + r;
                int gj = bxj * 128 + nb + j * 16 + (l & 15);
                float v = (gj > gk) ? sigm(acc[i][j][r]) : 0.f;
                ushort_t h = f2b(v), lo = f2b(v - b2f(h));
                lh[(size_t)gk * 2048 + gj] = h;
                ll[(size_t)gk * 2048 + gj] = lo;
            }
}

// ---- scores = qc_s@kc^T - silu(t1 @ look^T), store fp32 (k<=i) ------------------
__global__ __launch_bounds__(256) void k_scores(const ushort_t* __restrict__ t1h,
                                                const ushort_t* __restrict__ t1l,
                                                const ushort_t* __restrict__ lkh,
                                                const ushort_t* __restrict__ lkl,
                                                const ushort_t* __restrict__ qh,
                                                const ushort_t* __restrict__ ql,
                                                float* __restrict__ sc, int g0) {
    const int bxk = blockIdx.x, byi = blockIdx.y;
    if (bxk > byi) return;
    const int z = blockIdx.z, hh = g0 + z;
    const ushort_t* th = t1h + (size_t)z * 4194304;
    const ushort_t* tl = t1l + (size_t)z * 4194304;
    const ushort_t* lh = lkh + (size_t)z * 4194304;
    const ushort_t* ll = lkl + (size_t)z * 4194304;
    __shared__ ushort_t Ah[128 * P], Al[128 * P], Bh[128 * P], Bl[128 * P];
    f32x4 acc[4][4] = {};
    const int l = threadIdx.x & 63, w = threadIdx.x >> 6;
    const int mb = (w >> 1) * 64, nb = (w & 1) * 64;
    // Su phase: j-blocks [bxk, byi]
    for (int jb = bxk; jb <= byi; ++jb)
        for (int k0 = 0; k0 < 128; k0 += 32) {
            stage_hl(th + (size_t)(byi * 128) * 2048 + jb * 128 + k0,
                     tl + (size_t)(byi * 128) * 2048 + jb * 128 + k0, 2048, 128, Ah, Al);
            stage_hl(lh + (size_t)(bxk * 128) * 2048 + jb * 128 + k0,
                     ll + (size_t)(bxk * 128) * 2048 + jb * 128 + k0, 2048, 128, Bh, Bl);
            __syncthreads();
            mm_hl_4x4(Ah, Al, Bh, Bl, mb, nb, l, acc);
            __syncthreads();
        }
    // scores := -silu(Su), then accumulate Sc on top via MFMA
#pragma unroll
    for (int i = 0; i < 4; ++i)
#pragma unroll
        for (int j = 0; j < 4; ++j)
#pragma unroll
            for (int r = 0; r < 4; ++r) acc[i][j][r] = -silu(acc[i][j][r]);
    const size_t qco = (size_t)(3 * 16 + hh) * 131072, kco = (size_t)(4 * 16 + hh) * 131072;
    for (int k0 = 0; k0 < DH; k0 += 32) {
        stage_hl(qh + qco + (size_t)(byi * 128) * 64 + k0, ql + qco + (size_t)(byi * 128) * 64 + k0, 64, 128, Ah, Al);
        stage_hl(qh + kco + (size_t)(bxk * 128) * 64 + k0, ql + kco + (size_t)(bxk * 128) * 64 + k0, 64, 128, Bh, Bl);
        __syncthreads();
        mm_hl_4x4(Ah, Al, Bh, Bl, mb, nb, l, acc);
        __syncthreads();
    }
    float* so = sc + (size_t)z * 4194304;
#pragma unroll
    for (int i = 0; i < 4; ++i)
#pragma unroll
        for (int j = 0; j < 4; ++j)
#pragma unroll
            for (int r = 0; r < 4; ++r) {
                int gi = byi * 128 + mb + i * 16 + (l >> 4) * 4 + r;
                int gk = bxk * 128 + nb + j * 16 + (l & 15);
                if (gk <= gi) so[(size_t)gi * 2048 + gk] = acc[i][j][r];
            }
}

// ---- row softmax (k<=i) -> bf16 attn (zero-padded row) --------------------------
__global__ __launch_bounds__(256) void k_softmax(const float* __restrict__ sc,
                                                 ushort_t* __restrict__ attn) {
    const int z = blockIdx.x >> 11, i = blockIdx.x & 2047;
    const float* row = sc + ((size_t)z * 2048 + i) * 2048;
    ushort_t* arow = attn + ((size_t)z * 2048 + i) * 2048;
    const int nv = i + 1, tid = threadIdx.x;
    __shared__ float red[256];
    float m = -INFINITY;
    for (int k = tid; k < nv; k += 256) m = fmaxf(m, row[k]);
    red[tid] = m;
    __syncthreads();
    for (int s = 128; s; s >>= 1) {
        if (tid < s) red[tid] = fmaxf(red[tid], red[tid + s]);
        __syncthreads();
    }
    m = red[0];
    __syncthreads();
    float sum = 0.f;
    for (int k = tid; k < nv; k += 256) sum += expf(row[k] - m);
    red[tid] = sum;
    __syncthreads();
    for (int s = 128; s; s >>= 1) {
        if (tid < s) red[tid] += red[tid + s];
        __syncthreads();
    }
    const float inv = 1.f / red[0];
    for (int k = tid; k < nv; k += 256) arow[k] = f2b(expf(row[k] - m) * inv);
    for (int k = nv + tid; k < 2048; k += 256) arow[k] = 0;
}

// ---- pv: attno[b*2048+i][h*64+d] = attn @ vc  (via vcT) -------------------------
__global__ __launch_bounds__(256) void k_pv(const ushort_t* __restrict__ attn,
                                            const ushort_t* __restrict__ vcT,
                                            ushort_t* __restrict__ attno, int g0) {
    const int byi = blockIdx.x, z = blockIdx.y, hh = g0 + z;
    const int b = hh >> 3, h = hh & 7;
    __shared__ ushort_t Ah[128 * P], Bh[128 * P];
    f32x4 acc[2][4] = {};
    const int l = threadIdx.x & 63, w = threadIdx.x >> 6;
    const int mb = w * 32;
    const ushort_t* ap = attn + (size_t)z * 4194304 + (size_t)(byi * 128) * 2048;
    const ushort_t* vp = vcT + (size_t)hh * 131072;
    for (int kb = 0; kb <= byi; ++kb)
        for (int k0 = 0; k0 < 128; k0 += 32) {
            stage_s(ap + kb * 128 + k0, 2048, 128, Ah);
            stage_s(vp + kb * 128 + k0, 2048, 64, Bh);
            __syncthreads();
            mm_s_2x4(Ah, Bh, mb, 0, l, acc);
            __syncthreads();
        }
#pragma unroll
    for (int i = 0; i < 2; ++i)
#pragma unroll
        for (int j = 0; j < 4; ++j)
#pragma unroll
            for (int r = 0; r < 4; ++r) {
                int gi = byi * 128 + mb + i * 16 + (l >> 4) * 4 + r;
                int d = j * 16 + (l & 15);
                attno[((size_t)(b * 2048 + gi)) * 512 + h * 64 + d] = f2b(acc[i][j][r]);
            }
}

// ---- final = attno @ Wout^T ------------------------------------------------------
__global__ __launch_bounds__(256) void k_outproj(const ushort_t* __restrict__ attno,
                                                 const float* __restrict__ Wout,
                                                 float* __restrict__ out) {
    __shared__ ushort_t Ah[128 * P], Bh[128 * P];
    f32x4 acc[4][4] = {};
    const int m0 = blockIdx.y * 128, n0 = blockIdx.x * 128;
    const int l = threadIdx.x & 63, w = threadIdx.x >> 6;
    const int mb = (w >> 1) * 64, nb = (w & 1) * 64;
    for (int k0 = 0; k0 < DI; k0 += 32) {
        stage_s(attno + (size_t)m0 * DI + k0, DI, 128, Ah);
        stage_f32_s(Wout + (size_t)n0 * DI + k0, DI, 128, Bh);
        __syncthreads();
        mm_s_4x4(Ah, Bh, mb, nb, l, acc);
        __syncthreads();
    }
#pragma unroll
    for (int i = 0; i < 4; ++i)
#pragma unroll
        for (int j = 0; j < 4; ++j)
#pragma unroll
            for (int r = 0; r < 4; ++r) {
                int m = m0 + mb + i * 16 + (l >> 4) * 4 + r;
                int n = n0 + nb + j * 16 + (l & 15);
                out[(size_t)m * DM + n] = acc[i][j][r];
            }
}

extern "C" void kernel_launch(void* const* d_in, const int* in_sizes, int n_in,
                              void* d_out, int out_size, void* d_ws, size_t ws_size,
                              hipStream_t stream) {
    const float* x = (const float*)d_in[0];
    const float* Wqkv = (const float*)d_in[1];
    const float* Wout = (const float*)d_in[2];
    float* out = (float*)d_out;

    const size_t fixedb = 58720256ull;   // qkv hi/lo + vcT + attno
    const size_t perh = 50331648ull;     // t1 hi/lo + look hi/lo + sc   (per head)
    int g = 0;
    for (int cand : {16, 8, 4, 2, 1})
        if (fixedb + perh * (size_t)cand <= ws_size) { g = cand; break; }
    if (!g) return;

    ushort_t* qh = (ushort_t*)d_ws;              // 12,582,912 el
    ushort_t* ql = qh + 12582912;                // 12,582,912 el
    ushort_t* vcT = ql + 12582912;               // 2,097,152 el
    ushort_t* attno = vcT + 2097152;             // 2,097,152 el
    ushort_t* t1h = attno + 2097152;             // g * 4,194,304
    ushort_t* t1l = t1h + (size_t)g * 4194304;
    ushort_t* lkh = t1l + (size_t)g * 4194304;
    ushort_t* lkl = lkh + (size_t)g * 4194304;
    float* scb = (float*)(lkl + (size_t)g * 4194304);  // g * 4,194,304 f32

    k_proj<<<dim3(24, 32), 256, 0, stream>>>(x, Wqkv, qh, ql, vcT);

    for (int g0 = 0; g0 < 16; g0 += g) {
        dim3 grid(16, 16, g);
        k_t1<<<grid, 256, 0, stream>>>(qh, ql, t1h, t1l, g0);
        k_look<<<grid, 256, 0, stream>>>(qh, ql, lkh, lkl, g0);
        k_scores<<<grid, 256, 0, stream>>>(t1h, t1l, lkh, lkl, qh, ql, scb, g0);
        k_softmax<<<dim3(2048 * g), 256, 0, stream>>>(scb, t1h);
        k_pv<<<dim3(16, g), 256, 0, stream>>>(t1h, vcT, attno, g0);
    }

    k_outproj<<<dim3(8, 32), 256, 0, stream>>>(attno, Wout, out);
}